// Round 1
// baseline (494.838 us; speedup 1.0000x reference)
//
#include <hip/hip_runtime.h>
#include <hip/hip_bf16.h>

#define BM 128
#define BK 64
#define CHUNK 4096
#define LF 64
#define NBAGS 5
#define BROWS 2048
#define OUTC 320

typedef __attribute__((ext_vector_type(8))) short short8;
typedef __attribute__((ext_vector_type(4))) float f32x4;

struct BagArgs {
    const int*   A[NBAGS];
    const float* W[NBAGS];
    int K[NBAGS];
    int cstart[NBAGS + 1];
};

__device__ __forceinline__ unsigned short f2bf(float f) {
    unsigned u = __float_as_uint(f);
    u += 0x7FFFu + ((u >> 16) & 1u);   // round-to-nearest-even
    return (unsigned short)(u >> 16);
}

__global__ __launch_bounds__(256) void bag_gemm(BagArgs args,
                                                float* __restrict__ out,
                                                int* __restrict__ sums) {
    // A tile: [128 rows][64 k] bf16, XOR-swizzled. 16 KB
    __shared__ unsigned short lsA[BM * BK];
    // W^T tile: [64 cols][64 k] bf16, XOR-swizzled. 8 KB
    __shared__ unsigned short lsB[LF * BK];

    const int tid  = threadIdx.x;
    const int wave = tid >> 6;
    const int lane = tid & 63;

    // resolve (bag, chunk) from blockIdx.y
    int y = blockIdx.y;
    int bag = 0;
#pragma unroll
    for (int b = 1; b < NBAGS; ++b)
        if (y >= args.cstart[b]) bag = b;
    const int chunk = y - args.cstart[bag];
    const int K     = args.K[bag];
    const int k0    = chunk * CHUNK;
    const int kend  = min(k0 + CHUNK, K);
    const int m0    = blockIdx.x * BM;
    const int*   __restrict__ A = args.A[bag];
    const float* __restrict__ W = args.W[bag];

    f32x4 acc[2][4];
#pragma unroll
    for (int i = 0; i < 2; ++i)
#pragma unroll
        for (int j = 0; j < 4; ++j)
            acc[i][j] = (f32x4){0.f, 0.f, 0.f, 0.f};

    // A staging role: 4 threads per row, rows ar and ar+64
    const int ar = tid >> 2;   // 0..63
    const int aj = tid & 3;
    // W staging role: 1 thread per k-row, 16 cols each (conflict-free banks)
    const int wk = tid & 63;   // local k row 0..63
    const int wc0 = (tid >> 6) * 16;

    int sum0 = 0, sum1 = 0;

    for (int kk = k0; kk < kend; kk += BK) {
        // ---------- stage A (int32 {0,1} -> bf16), accumulate popcounts ----------
#pragma unroll
        for (int half = 0; half < 2; ++half) {
            const int r = ar + half * 64;
            const size_t rowoff = (size_t)(m0 + r) * (size_t)K;
#pragma unroll
            for (int i = 0; i < 4; ++i) {
                const int col = kk + aj * 4 + i * 16;
                int4 v = make_int4(0, 0, 0, 0);
                if (col < kend) v = *(const int4*)(A + rowoff + col);
                const int s = v.x + v.y + v.z + v.w;
                if (half == 0) sum0 += s; else sum1 += s;
                unsigned p0 = (v.x ? 0x3F80u : 0u) | (v.y ? 0x3F800000u : 0u);
                unsigned p1 = (v.z ? 0x3F80u : 0u) | (v.w ? 0x3F800000u : 0u);
                int kbyte = (aj * 4 + i * 16) * 2;
                kbyte ^= (r & 7) << 4;
                *(uint2*)((char*)lsA + r * (BK * 2) + kbyte) = make_uint2(p0, p1);
            }
        }
        // ---------- stage W^T (f32 -> bf16), transposed scatter ----------
        {
            const int gk = kk + wk;
#pragma unroll
            for (int u = 0; u < 4; ++u) {
                float4 w = make_float4(0.f, 0.f, 0.f, 0.f);
                if (gk < kend) w = *(const float4*)(W + (size_t)gk * LF + wc0 + u * 4);
                const unsigned short b0 = f2bf(w.x), b1 = f2bf(w.y),
                                     b2 = f2bf(w.z), b3 = f2bf(w.w);
                const unsigned short bs[4] = {b0, b1, b2, b3};
#pragma unroll
                for (int v2 = 0; v2 < 4; ++v2) {
                    const int c = wc0 + u * 4 + v2;
                    const int kbyte = (wk * 2) ^ ((c & 7) << 4);
                    *(unsigned short*)((char*)lsB + c * (BK * 2) + kbyte) = bs[v2];
                }
            }
        }
        __syncthreads();

        // ---------- MFMA ----------
        const int fr   = lane & 15;
        const int kgrp = lane >> 4;
#pragma unroll
        for (int kh = 0; kh < 2; ++kh) {
            const int kbyteR = kh * 64 + kgrp * 16;
            short8 afr[2];
#pragma unroll
            for (int mi = 0; mi < 2; ++mi) {
                const int row = wave * 32 + mi * 16 + fr;
                const int off = row * (BK * 2) + (kbyteR ^ ((row & 7) << 4));
                afr[mi] = *(const short8*)((const char*)lsA + off);
            }
#pragma unroll
            for (int ni = 0; ni < 4; ++ni) {
                const int colB = ni * 16 + fr;
                const int offb = colB * (BK * 2) + (kbyteR ^ ((colB & 7) << 4));
                const short8 bfr = *(const short8*)((const char*)lsB + offb);
#pragma unroll
                for (int mi = 0; mi < 2; ++mi)
                    acc[mi][ni] = __builtin_amdgcn_mfma_f32_16x16x32_bf16(
                        afr[mi], bfr, acc[mi][ni], 0, 0, 0);
            }
        }
        __syncthreads();
    }

    // ---------- row-popcount reduce (4 lanes per row) + atomic ----------
    sum0 += __shfl_xor(sum0, 1);
    sum0 += __shfl_xor(sum0, 2);
    sum1 += __shfl_xor(sum1, 1);
    sum1 += __shfl_xor(sum1, 2);
    if (aj == 0) {
        atomicAdd(&sums[bag * BROWS + m0 + ar], sum0);
        atomicAdd(&sums[bag * BROWS + m0 + ar + 64], sum1);
    }

    // ---------- split-K accumulate into output ----------
    const int fr = lane & 15;
    const int rg = lane >> 4;
#pragma unroll
    for (int mi = 0; mi < 2; ++mi)
#pragma unroll
        for (int ni = 0; ni < 4; ++ni)
#pragma unroll
            for (int r = 0; r < 4; ++r) {
                const int row = m0 + wave * 32 + mi * 16 + rg * 4 + r;
                const int col = bag * LF + ni * 16 + fr;
                atomicAdd(&out[row * OUTC + col], acc[mi][ni][r]);
            }
}

__global__ __launch_bounds__(256) void norm_fix(float* __restrict__ out,
                                                const int* __restrict__ sums) {
    const int idx = blockIdx.x * blockDim.x + threadIdx.x;
    if (idx >= BROWS * OUTC) return;
    const int m = idx / OUTC;
    const int c = idx % OUTC;
    const int bag = c >> 6;
    float v = out[idx];
    if (bag == 0) {
        // faithful reference bug: decades normalized by dec sums AND movie sums
        const int s0 = sums[m];
        const int s1 = sums[BROWS + m];
        if (s0) v /= (float)s0;
        if (s1) v /= (float)s1;
    } else if (bag >= 2) {
        const int s = sums[bag * BROWS + m];
        if (s) v /= (float)s;
    }
    out[idx] = v;
}

extern "C" void kernel_launch(void* const* d_in, const int* in_sizes, int n_in,
                              void* d_out, int out_size, void* d_ws, size_t ws_size,
                              hipStream_t stream) {
    float* out = (float*)d_out;
    int* sums = (int*)d_ws;

    hipMemsetAsync(d_out, 0, (size_t)out_size * sizeof(float), stream);
    hipMemsetAsync(sums, 0, NBAGS * BROWS * sizeof(int), stream);

    BagArgs args;
    const int Ks[NBAGS] = {12, 60000, 32, 100000, 20000};
    int total = 0;
    for (int b = 0; b < NBAGS; ++b) {
        args.A[b] = (const int*)d_in[b];
        args.W[b] = (const float*)d_in[5 + b];
        args.K[b] = Ks[b];
        args.cstart[b] = total;
        total += (Ks[b] + CHUNK - 1) / CHUNK;
    }
    args.cstart[NBAGS] = total;   // 47 chunks -> grid (16, 47) = 752 blocks

    dim3 grid(BROWS / BM, total);
    bag_gemm<<<grid, 256, 0, stream>>>(args, out, sums);

    const int n = BROWS * OUTC;
    norm_fix<<<(n + 255) / 256, 256, 0, stream>>>(out, sums);
}